// Round 10
// baseline (82.631 us; speedup 1.0000x reference)
//
#include <hip/hip_runtime.h>
#include <math.h>

#ifndef M_PI
#define M_PI 3.14159265358979323846
#endif

typedef _Float16 half8v __attribute__((ext_vector_type(8)));
typedef _Float16 half2v __attribute__((ext_vector_type(2)));
typedef float float4v __attribute__((ext_vector_type(4)));

constexpr int KDIM = 128;
constexpr int LTOT = 8192;
constexpr int TILE_L = 64;
constexpr int NT = 256;
constexpr int WSTR = 136;   // LDS row stride in halves (128 + 8 pad)

// ---------------------------------------------------------------------------
// Single kernel (no workspace, fully deterministic). Per 64-point tile:
//   wx/wy  : Dirichlet weights via rotation recurrence (validated R3/R6/R7/R8)
//   tmp    = psi * WX via mfma_f32_16x16x32_f16
//   C_b    = sum (-1)^{p+q} psi, accumulated from the GEMM's own A loads
//   out[l] = (sum_p wy[p][l]*tmp[p][l] - sin64x*sin64y*C_b) / K^2
// RULES (hard-won, R4/R5/R9 failures):
//   1. Never hold A-fragment registers live across the unrolled build loop —
//      a_raw is loaded strictly after it.
//   2. Keep the build loop simple-scalar (no packed vectors / lambdas /
//      nested ternaries inside it) — every complexity increase corrupted.
// ---------------------------------------------------------------------------
__global__ __launch_bounds__(NT, 4) void main_kernel(const float* __restrict__ x0,
        const float* __restrict__ y0, const float* __restrict__ psi,
        float* __restrict__ out) {
    __shared__ _Float16 wxT[TILE_L][WSTR];         // [l][q]
    __shared__ _Float16 wyT[TILE_L][WSTR];         // [l][p]
    __shared__ float ndh[KDIM], ndl[KDIM], ndh2[KDIM], ndl2[KDIM];
    __shared__ float s64A[2][TILE_L];
    __shared__ float partial[4][TILE_L];
    __shared__ float cbred[4];

    const int tid = threadIdx.x;
    const int lane = tid & 63;
    const int w = tid >> 6;
    const int bid = blockIdx.x;
    const int b = bid >> 7;
    const int l0 = (bid & 127) * TILE_L;
    const int qd = lane >> 4;          // quad 0..3
    const int ln = lane & 15;

    const float* Pb = psi + (size_t)b * 16384;

    // ---- node tables for the rare slow path ----
    if (tid < KDIM) {
        double d = (double)tid * (M_PI / 64.0);
        float h = (float)d;
        ndh[tid] = h; ndl[tid] = (float)(d - (double)h);
        double d2 = d - 2.0 * M_PI;
        float h2 = (float)d2;
        ndh2[tid] = h2; ndl2[tid] = (float)(d2 - (double)h2);
    }

    // ---- per-thread build setup: one column (mat,l), q-range [64*hf, +64) ----
    const int col = tid & 127;
    const int mat = col >> 6;                      // 0 = wx, 1 = wy
    const int l = col & 63;
    const int hf = tid >> 7;
    const float* src = mat ? y0 : x0;
    const float pos = src[(size_t)b * LTOT + l0 + l];
    const float s64 = sinf(64.0f * pos);
    float sa, ca;
    sincosf(0.5f * pos, &sa, &ca);
    float cs_s, cs_c;                              // seed: sin/cos(pos/2 - 64*hf*beta)
    if (hf == 0) { cs_s = sa; cs_c = ca; s64A[mat][l] = s64; }
    else         { cs_s = -ca; cs_c = sa; }        // exact rotate by -pi/2
    __syncthreads();

    // ---- build: w(t_q) = (-1)^q sin(64 pos) * cos(th)/sin(th), th = pos/2 - q*beta
    _Float16* dst = mat ? &wyT[l][0] : &wxT[l][0];
    const float CB  = 0.9996988186962042f,  SB  = 0.024541228522912288f;  // beta = pi/128
    const float C16 = 0.9238795325112867f,  S16 = 0.3826834323650898f;    // 16*beta
    const float step = (float)(M_PI / 64.0);
#pragma unroll
    for (int kk = 0; kk < 4; ++kk) {
        float ws_ = cs_s, wc_ = cs_c;
        const int q0 = 64 * hf + 16 * kk;
#pragma unroll
        for (int h8 = 0; h8 < 2; ++h8) {
            _Float16 buf[8];
#pragma unroll
            for (int j = 0; j < 8; ++j) {
                const int q = q0 + 8 * h8 + j;
                const float num = (j & 1) ? -s64 : s64;   // sin(64 t_q) exactly
                float wv;
                if (__builtin_expect(fabsf(ws_) >= 2e-3f, 1)) {
                    wv = num * wc_ * __builtin_amdgcn_rcpf(ws_);
                } else {
                    // near grid node: rebuild u = t_q in two-float, Taylor ratio
                    float ta = pos - step * (float)q;
                    float nh, nl;
                    if (ta > -1.0f) { nh = ndh[q];  nl = ndl[q]; }
                    else            { nh = ndh2[q]; nl = ndl2[q]; }
                    float u = (pos - nh) - nl;
                    if (fabsf(u) < 1e-7f) {
                        wv = 128.0f;
                    } else {
                        float hh = 0.5f * u;
                        float s2 = hh * (1.0f - 0.16666667f * hh * hh);
                        float c2 = 1.0f - 0.5f * hh * hh;
                        wv = num * c2 * __builtin_amdgcn_rcpf(s2);
                    }
                }
                buf[j] = (_Float16)wv;
                float ns = ws_ * CB - wc_ * SB;    // rotate by -beta
                wc_ = wc_ * CB + ws_ * SB;
                ws_ = ns;
            }
            *(half8v*)&dst[q0 + 8 * h8] = *(half8v*)buf;
        }
        float ns = cs_s * C16 - cs_c * S16;        // reseed: rotate by -16*beta
        cs_c = cs_c * C16 + cs_s * S16;
        cs_s = ns;
    }
    __syncthreads();

    // ---- A k0 load (fp32, L2/HBM), strictly AFTER the build ----
    float4v a_raw[2][2];
#pragma unroll
    for (int mi = 0; mi < 2; ++mi) {
        const float* rp = Pb + (32 * w + 16 * mi + ln) * 128 + 8 * qd;
        a_raw[mi][0] = *(const float4v*)(rp);
        a_raw[mi][1] = *(const float4v*)(rp + 4);
    }

    // ---- GEMM + in-flight C_b from the same A values ----
    float4v acc[2][4];
#pragma unroll
    for (int mi = 0; mi < 2; ++mi)
#pragma unroll
        for (int ni = 0; ni < 4; ++ni) acc[mi][ni] = (float4v){0.f, 0.f, 0.f, 0.f};

    float cbs = 0.0f;
#pragma unroll
    for (int k = 0; k < 4; ++k) {
        half8v af[2];
#pragma unroll
        for (int mi = 0; mi < 2; ++mi) {
#pragma unroll
            for (int j = 0; j < 4; ++j) {
                af[mi][j]     = (_Float16)a_raw[mi][0][j];
                af[mi][4 + j] = (_Float16)a_raw[mi][1][j];
            }
            cbs += (a_raw[mi][0].x - a_raw[mi][0].y) + (a_raw[mi][0].z - a_raw[mi][0].w)
                 + (a_raw[mi][1].x - a_raw[mi][1].y) + (a_raw[mi][1].z - a_raw[mi][1].w);
        }
        if (k < 3) {   // prefetch next k-step (af/cbs already captured the values)
#pragma unroll
            for (int mi = 0; mi < 2; ++mi) {
                const float* rp = Pb + (32 * w + 16 * mi + ln) * 128 + (k + 1) * 32 + 8 * qd;
                a_raw[mi][0] = *(const float4v*)(rp);
                a_raw[mi][1] = *(const float4v*)(rp + 4);
            }
        }
#pragma unroll
        for (int ni = 0; ni < 4; ++ni) {
            half8v bf = *(const half8v*)&wxT[16 * ni + ln][k * 32 + 8 * qd];
#pragma unroll
            for (int mi = 0; mi < 2; ++mi)
                acc[mi][ni] = __builtin_amdgcn_mfma_f32_16x16x32_f16(af[mi], bf, acc[mi][ni], 0, 0, 0);
        }
    }

    // row-parity sign, deterministic wave reduction, one partial per wave
    if (ln & 1) cbs = -cbs;
#pragma unroll
    for (int off = 1; off < 64; off <<= 1) cbs += __shfl_xor(cbs, off, 64);
    if (lane == 0) cbred[w] = cbs;

    // ---- reduce over p: C/D layout p = 32w+16mi+4qd+reg, l = 16ni+ln ----
    float part[4];
#pragma unroll
    for (int ni = 0; ni < 4; ++ni) {
        float s = 0.f;
#pragma unroll
        for (int mi = 0; mi < 2; ++mi) {
            const _Float16* wp = &wyT[16 * ni + ln][32 * w + 16 * mi + 4 * qd];
            half2v w01 = *(const half2v*)(wp);
            half2v w23 = *(const half2v*)(wp + 2);
            s += acc[mi][ni][0] * (float)w01[0] + acc[mi][ni][1] * (float)w01[1]
               + acc[mi][ni][2] * (float)w23[0] + acc[mi][ni][3] * (float)w23[1];
        }
        s += __shfl_xor(s, 16, 64);
        s += __shfl_xor(s, 32, 64);
        part[ni] = s;
    }
    if (qd == 0) {
#pragma unroll
        for (int ni = 0; ni < 4; ++ni) partial[w][16 * ni + ln] = part[ni];
    }
    __syncthreads();

    if (tid < TILE_L) {
        float cb = (cbred[0] + cbred[1]) + (cbred[2] + cbred[3]);
        float s = (partial[0][tid] + partial[1][tid]) + (partial[2][tid] + partial[3][tid]);
        s -= s64A[0][tid] * s64A[1][tid] * cb;
        out[(size_t)b * LTOT + l0 + tid] = s * (1.0f / 16384.0f);
    }
}

extern "C" void kernel_launch(void* const* d_in, const int* in_sizes, int n_in,
                              void* d_out, int out_size, void* d_ws, size_t ws_size,
                              hipStream_t stream) {
    const float* x0  = (const float*)d_in[0];
    const float* y0  = (const float*)d_in[1];
    const float* psi = (const float*)d_in[2];
    float* out = (float*)d_out;
    (void)d_ws; (void)ws_size;   // unused: single self-contained kernel

    main_kernel<<<16 * (LTOT / TILE_L), NT, 0, stream>>>(x0, y0, psi, out);
}